// Round 7
// baseline (34109.573 us; speedup 1.0000x reference)
//
#include <hip/hip_runtime.h>
#include <stdint.h>

#define BSZ 512
#define TT  256
#define IIN 64
#define HH  512
#define NSTEPS 10
#define NBLOCKS 256

typedef unsigned short ushort_t;
typedef short bf16x8 __attribute__((ext_vector_type(8)));
typedef float f32x4  __attribute__((ext_vector_type(4)));

static constexpr size_t W0TILE = 256*576;        // role0 per-n-tile elems
static constexpr size_t W1TILE = 256*1024;       // role1
static constexpr size_t N0W = 8*W0TILE;
static constexpr size_t NTW = N0W + 8*W1TILE;

__device__ __forceinline__ ushort_t f2bf(float f){
  union { float f; uint32_t u; } v; v.f = f;
  uint32_t u = v.u;
  return (ushort_t)((u + 0x7fffu + ((u >> 16) & 1u)) >> 16);
}
__device__ __forceinline__ float bf2f(ushort_t h){
  union { uint32_t u; float f; } v; v.u = ((uint32_t)h) << 16;
  return v.f;
}
__device__ __forceinline__ void split2(float f, ushort_t& h, ushort_t& l){
  h = f2bf(f); l = f2bf(f - bf2f(h));
}
__device__ __forceinline__ float sigf(float x){ return 1.0f/(1.0f+__expf(-x)); }
__device__ __forceinline__ float tanhfast(float x){ return 1.0f - 2.0f/(__expf(2.0f*x)+1.0f); }

__device__ __forceinline__ unsigned long long aload64(const uint32_t* p){
  return __hip_atomic_load((const unsigned long long*)(const void*)p,
                           __ATOMIC_RELAXED, __HIP_MEMORY_SCOPE_AGENT);
}
__device__ __forceinline__ void astore32(uint32_t* p, uint32_t v){
  __hip_atomic_store(p, v, __ATOMIC_RELAXED, __HIP_MEMORY_SCOPE_AGENT);
}
__device__ __forceinline__ uint32_t aload32(const uint32_t* p){
  return __hip_atomic_load(p, __ATOMIC_RELAXED, __HIP_MEMORY_SCOPE_AGENT);
}

__device__ __forceinline__ int get_xcd(){
  unsigned v;
  asm volatile("s_getreg_b32 %0, hwreg(HW_REG_XCC_ID)" : "=s"(v));
  return (int)(v & 7);
}

struct KP {
  const float* x;
  const ushort_t *Wh, *Wl;
  const float *b0v, *b1v;
  const float *Wlin, *blin;
  uint32_t *h0a, *h0b, *h1a, *h1b;   // packed h (hi | lo<<16) double buffers
  float *c0m, *c1m;                  // fallback c
  uint32_t *outp;
  float* out;
  uint32_t *bar, *rel, *assign;
};

// LDS A layout: chunk c (32 k) x row r (0..15): 8 16B-units, XOR-swizzled.
__device__ __forceinline__ int lds_base(int c, int r){ return (c*16 + r)*64; }

// issue-first staging of packed h (NU 8-elem units per row, 16 rows)
template<int NU>
struct StageP {
  static constexpr int NTASK = NU*16;
  static constexpr int TPT = (NTASK + 255)/256;
  unsigned long long q[TPT][4];
  __device__ __forceinline__ void issue(const uint32_t* src, int rowbase, int stride){
    #pragma unroll
    for (int i=0;i<TPT;++i){
      const int t = i*256 + (int)threadIdx.x;
      if (NTASK % 256 == 0 || t < NTASK){
        const int r = t / NU, uk = t - r*NU;
        const uint32_t* sp = src + (size_t)(rowbase+r)*stride + uk*8;
        q[i][0]=aload64(sp);   q[i][1]=aload64(sp+2);
        q[i][2]=aload64(sp+4); q[i][3]=aload64(sp+6);
      }
    }
  }
  __device__ __forceinline__ void commit(ushort_t* lds, int cbase){
    #pragma unroll
    for (int i=0;i<TPT;++i){
      const int t = i*256 + (int)threadIdx.x;
      if (NTASK % 256 == 0 || t < NTASK){
        const int r = t / NU, uk = t - r*NU;
        union { ushort_t us[8]; bf16x8 v; } H, L;
        #pragma unroll
        for (int j=0;j<4;++j){
          uint32_t a2=(uint32_t)q[i][j], b2=(uint32_t)(q[i][j]>>32);
          H.us[2*j]  =(ushort_t)a2; L.us[2*j]  =(ushort_t)(a2>>16);
          H.us[2*j+1]=(ushort_t)b2; L.us[2*j+1]=(ushort_t)(b2>>16);
        }
        const int c = cbase + (uk>>2), u = uk&3;
        const int sh = (u | ((c&1)<<2)) ^ (r&7);
        const int sl = (u | (((c&1)^1)<<2)) ^ (r&7);
        *(bf16x8*)&lds[lds_base(c,r)+sh*8] = H.v;
        *(bf16x8*)&lds[lds_base(c,r)+sl*8] = L.v;
      }
    }
  }
};

// f32 x staging: 16 rows x 64 k -> chunks cbase..cbase+1
struct StageF {
  f32x4 v0, v1;
  __device__ __forceinline__ void issue(const float* src, int rowbase, int stride){
    const int t = threadIdx.x;
    if (t < 128){
      const int r = t>>3, uk = t&7;
      const float* sp = src + (size_t)(rowbase+r)*stride + uk*8;
      v0 = *(const f32x4*)sp; v1 = *(const f32x4*)(sp+4);
    }
  }
  __device__ __forceinline__ void commit(ushort_t* lds, int cbase){
    const int t = threadIdx.x;
    if (t < 128){
      const int r = t>>3, uk = t&7;
      union { ushort_t us[8]; bf16x8 v; } H, L;
      #pragma unroll
      for (int j=0;j<4;++j){
        split2(v0[j], H.us[j],   L.us[j]);
        split2(v1[j], H.us[4+j], L.us[4+j]);
      }
      const int c = cbase + (uk>>2), u = uk&3;
      const int sh = (u | ((c&1)<<2)) ^ (r&7);
      const int sl = (u | (((c&1)^1)<<2)) ^ (r&7);
      *(bf16x8*)&lds[lds_base(c,r)+sh*8] = H.v;
      *(bf16x8*)&lds[lds_base(c,r)+sl*8] = L.v;
    }
  }
};

// ---------------------------------------------------------------------------
// One cell (16 rows x 256 gate-cols), fully unrolled K. Wave w: h-cols
// [w*16..+16), gates s=0..3. A chunks at LDS cofs.., B streamed from L2.
// ---------------------------------------------------------------------------
template<int NCH, int COFS, bool CMEM>
__device__ __forceinline__ void cell_compute2(const ushort_t* lds,
    const ushort_t* __restrict__ wh, const ushort_t* __restrict__ wl,
    int m, const float* bjs, float* cr, float* cmem,
    uint32_t* houtp, int jcol)
{
  const int tid = threadIdx.x;
  const int w = tid >> 6, l = tid & 63;
  const int lr = l & 15, kq = l >> 4;
  const int clb = w*64 + lr;
  f32x4 acc[4];
  #pragma unroll
  for (int s=0;s<4;++s) acc[s] = (f32x4){0.f,0.f,0.f,0.f};

  #pragma unroll
  for (int c=0;c<NCH;++c){
    const int cp = c + COFS;
    const int shi = (kq | ((cp&1)<<2)) ^ (lr&7);
    const int slo = (kq | (((cp&1)^1)<<2)) ^ (lr&7);
    const bf16x8 ah = *(const bf16x8*)&lds[lds_base(cp,lr)+shi*8];
    const bf16x8 al = *(const bf16x8*)&lds[lds_base(cp,lr)+slo*8];
    #pragma unroll
    for (int s=0;s<4;++s){
      const size_t bo = ((size_t)(c*256 + clb + s*16))*32 + kq*8;
      const bf16x8 bh = *(const bf16x8*)&wh[bo];
      const bf16x8 bl = *(const bf16x8*)&wl[bo];
      acc[s] = __builtin_amdgcn_mfma_f32_16x16x32_bf16(ah, bh, acc[s],0,0,0);
      acc[s] = __builtin_amdgcn_mfma_f32_16x16x32_bf16(ah, bl, acc[s],0,0,0);
      acc[s] = __builtin_amdgcn_mfma_f32_16x16x32_bf16(al, bh, acc[s],0,0,0);
    }
  }
  #pragma unroll
  for (int q=0;q<4;++q){
    const int row = m*16 + kq*4 + q;
    float gi = acc[0][q]+bjs[0], gf = acc[1][q]+bjs[1];
    float gg = acc[2][q]+bjs[2], go = acc[3][q]+bjs[3];
    const size_t cidx = ((size_t)row << 9) + jcol;
    float cold = CMEM ? cmem[cidx] : cr[q];
    float cn = sigf(gf)*cold + sigf(gi)*tanhfast(gg);
    if (CMEM) cmem[cidx] = cn; else cr[q] = cn;
    float hv = sigf(go)*tanhfast(cn);
    ushort_t hh2, hl2; split2(hv, hh2, hl2);
    astore32(&houtp[cidx], (uint32_t)hh2 | ((uint32_t)hl2 << 16));
  }
}

// ---- merged phase bodies ----
template<bool CMEM>
__device__ __forceinline__ void enc_body(const KP& p, ushort_t* lds, int m, int n, int s,
    const float* b0r, const float* b1r, float* c0r, float* c1r, int jcol)
{
  uint32_t* h0[2] = { p.h0a, p.h0b };
  uint32_t* h1[2] = { p.h1a, p.h1b };
  const uint32_t* rd0 = h0[(s+1)&1];
  uint32_t* wr0 = h0[s&1];
  const uint32_t* rd1 = h1[s&1];
  uint32_t* wr1 = h1[(s+1)&1];
  StageF SX; StageP<64> S0; StageP<64> S1;
  if (s < TT) SX.issue(p.x + (size_t)s*IIN, m*16, TT*IIN);
  S0.issue(rd0, m*16, 512);
  if (s >= 1) S1.issue(rd1, m*16, 512);
  if (s < TT) SX.commit(lds, 0);
  S0.commit(lds, 2);
  if (s >= 1) S1.commit(lds, 18);
  __syncthreads();
  if (s < TT)
    cell_compute2<18,0,CMEM>(lds, p.Wh + (size_t)n*W0TILE, p.Wl + (size_t)n*W0TILE,
                             m, b0r, c0r, p.c0m, wr0, jcol);
  if (s >= 1)
    cell_compute2<32,2,CMEM>(lds, p.Wh + N0W + (size_t)n*W1TILE, p.Wl + N0W + (size_t)n*W1TILE,
                             m, b1r, c1r, p.c1m, wr1, jcol);
}

template<bool CMEM>
__device__ __forceinline__ void dec0_body(const KP& p, ushort_t* lds, int m, int n, int d, int p0,
    const float* b0r, float* c0r, int jcol)
{
  uint32_t* h0[2] = { p.h0a, p.h0b };
  StageF SX; StageP<8> SO; StageP<64> S0;
  if (d == 0) SX.issue(p.x + (size_t)(TT-1)*IIN, m*16, TT*IIN);
  else        SO.issue(p.outp, m*16, 64);
  S0.issue(h0[p0], m*16, 512);
  if (d == 0) SX.commit(lds, 0); else SO.commit(lds, 0);
  S0.commit(lds, 2);
  __syncthreads();
  cell_compute2<18,0,CMEM>(lds, p.Wh + (size_t)n*W0TILE, p.Wl + (size_t)n*W0TILE,
                           m, b0r, c0r, p.c0m, h0[1-p0], jcol);
}

template<bool CMEM>
__device__ __forceinline__ void dec1_body(const KP& p, ushort_t* lds, int m, int n, int p0, int p1,
    const float* b1r, float* c1r, int jcol)
{
  uint32_t* h0[2] = { p.h0a, p.h0b };
  uint32_t* h1[2] = { p.h1a, p.h1b };
  StageP<64> SA; StageP<64> SB;
  SA.issue(h0[1-p0], m*16, 512);
  SB.issue(h1[p1], m*16, 512);
  SA.commit(lds, 2); SB.commit(lds, 18);
  __syncthreads();
  cell_compute2<32,2,CMEM>(lds, p.Wh + N0W + (size_t)n*W1TILE, p.Wl + N0W + (size_t)n*W1TILE,
                           m, b1r, c1r, p.c1m, h1[1-p1], jcol);
}

__device__ __forceinline__ void lin_body(const KP& p, ushort_t* lds, int m, int d,
                                         const uint32_t* h1cur)
{
  float* lf = (float*)lds;                 // [16][512] f32 = 32 KB
  const int r0 = m*16;
  for (int tsk = threadIdx.x; tsk < 4096; tsk += 256){
    const int r = tsk >> 8, e2 = (tsk & 255)*2;
    unsigned long long q = aload64(h1cur + (size_t)(r0+r)*512 + e2);
    uint32_t a2 = (uint32_t)q, b2 = (uint32_t)(q>>32);
    lf[r*512 + e2]     = bf2f((ushort_t)a2) + bf2f((ushort_t)(a2>>16));
    lf[r*512 + e2 + 1] = bf2f((ushort_t)b2) + bf2f((ushort_t)(b2>>16));
  }
  __syncthreads();
  const int i = threadIdx.x & 63;
  const int rq = threadIdx.x >> 6;
  const float* wr = p.Wlin + (size_t)i*512;
  float sum[4] = {0.f,0.f,0.f,0.f};
  for (int k = 0; k < 512; k += 4){
    f32x4 wv = *(const f32x4*)(wr + k);
    #pragma unroll
    for (int q2=0;q2<4;++q2){
      const float* hfp = &lf[(rq*4+q2)*512 + k];
      sum[q2] += hfp[0]*wv[0] + hfp[1]*wv[1] + hfp[2]*wv[2] + hfp[3]*wv[3];
    }
  }
  #pragma unroll
  for (int q2=0;q2<4;++q2){
    const int row = r0 + rq*4 + q2;
    float v = sum[q2] + p.blin[i];
    p.out[(size_t)row*(NSTEPS*IIN) + d*IIN + i] = v;
    ushort_t oh, ol; split2(v, oh, ol);
    astore32(&p.outp[row*64 + i], (uint32_t)oh | ((uint32_t)ol<<16));
  }
  __syncthreads();
}

// ---- persistent kernel: XCD-ticket, issue-first staging, 8-line barrier ----
__global__ __launch_bounds__(256, 2)
void lstm_persist(KP p)
{
  __shared__ ushort_t lds[34816];   // 34 chunks x 16 x 64 ushorts = 68 KB
  __shared__ int s_lt;
  if (threadIdx.x == 0){
    const int xcd = get_xcd();
    int lt = 0;
    for (int a = 0; a < 8; ++a){
      const int xx = (xcd + a) & 7;
      uint32_t idx = __hip_atomic_fetch_add(&p.assign[xx], 1u, __ATOMIC_RELAXED,
                                            __HIP_MEMORY_SCOPE_AGENT);
      if (idx < 32u){ lt = xx*32 + (int)idx; break; }
    }
    s_lt = lt;
  }
  __syncthreads();
  const int lt = s_lt;
  const int n = lt >> 5;           // n == XCD -> 1.64 MB weight slice L2-resident
  const int m = lt & 31;

  const int jcol = n*64 + ((threadIdx.x >> 6) * 16) + (threadIdx.x & 15);
  float b0r[4] = { p.b0v[jcol], p.b0v[512+jcol], p.b0v[1024+jcol], p.b0v[1536+jcol] };
  float b1r[4] = { p.b1v[jcol], p.b1v[512+jcol], p.b1v[1024+jcol], p.b1v[1536+jcol] };
  float c0r[4] = {0.f,0.f,0.f,0.f};
  float c1r[4] = {0.f,0.f,0.f,0.f};

  const int bid = blockIdx.x;
  const int lane8 = bid & 7;
  int slot = 0;
  auto gbar = [&](){
    __syncthreads();
    if (threadIdx.x == 0){
      __hip_atomic_fetch_add(&p.bar[slot*8 + lane8], 1u, __ATOMIC_RELAXED,
                             __HIP_MEMORY_SCOPE_AGENT);
      if (bid == 0){
        for (;;){
          uint32_t s2 = 0;
          #pragma unroll
          for (int j2=0;j2<8;++j2) s2 += aload32(&p.bar[slot*8 + j2]);
          if (s2 == (uint32_t)NBLOCKS) break;
          __builtin_amdgcn_s_sleep(1);
        }
        __hip_atomic_store(&p.rel[slot], 1u, __ATOMIC_RELAXED, __HIP_MEMORY_SCOPE_AGENT);
      } else {
        while (!aload32(&p.rel[slot])) __builtin_amdgcn_s_sleep(1);
      }
    }
    __syncthreads();
    ++slot;
  };

  for (int s = 0; s <= TT; ++s){
    enc_body<false>(p, lds, m, n, s, b0r, b1r, c0r, c1r, jcol);
    gbar();
  }
  int p0 = 1, p1 = 1;
  uint32_t* h1[2] = { p.h1a, p.h1b };
  for (int d = 0; d < NSTEPS; ++d){
    dec0_body<false>(p, lds, m, n, d, p0, b0r, c0r, jcol);
    gbar();
    dec1_body<false>(p, lds, m, n, p0, p1, b1r, c1r, jcol);
    gbar();
    if (n == 0) lin_body(p, lds, m, d, h1[1-p1]);
    gbar();
    p0 ^= 1; p1 ^= 1;
  }
}

// ---- fallback per-step kernels (kernel boundaries give coherence; c in mem)
__global__ __launch_bounds__(256, 2)
void fb_enc(KP p, int s){
  __shared__ ushort_t lds[34816];
  const int m = blockIdx.x >> 3, n = blockIdx.x & 7;
  const int jcol = n*64 + ((threadIdx.x >> 6) * 16) + (threadIdx.x & 15);
  float b0r[4] = { p.b0v[jcol], p.b0v[512+jcol], p.b0v[1024+jcol], p.b0v[1536+jcol] };
  float b1r[4] = { p.b1v[jcol], p.b1v[512+jcol], p.b1v[1024+jcol], p.b1v[1536+jcol] };
  enc_body<true>(p, lds, m, n, s, b0r, b1r, nullptr, nullptr, jcol);
}
__global__ __launch_bounds__(256, 2)
void fb_dec0(KP p, int d, int p0){
  __shared__ ushort_t lds[34816];
  const int m = blockIdx.x >> 3, n = blockIdx.x & 7;
  const int jcol = n*64 + ((threadIdx.x >> 6) * 16) + (threadIdx.x & 15);
  float b0r[4] = { p.b0v[jcol], p.b0v[512+jcol], p.b0v[1024+jcol], p.b0v[1536+jcol] };
  dec0_body<true>(p, lds, m, n, d, p0, b0r, nullptr, jcol);
}
__global__ __launch_bounds__(256, 2)
void fb_dec1(KP p, int p0, int p1){
  __shared__ ushort_t lds[34816];
  const int m = blockIdx.x >> 3, n = blockIdx.x & 7;
  const int jcol = n*64 + ((threadIdx.x >> 6) * 16) + (threadIdx.x & 15);
  float b1r[4] = { p.b1v[jcol], p.b1v[512+jcol], p.b1v[1024+jcol], p.b1v[1536+jcol] };
  dec1_body<true>(p, lds, m, n, p0, p1, b1r, nullptr, jcol);
}
__global__ __launch_bounds__(256)
void fb_lin(KP p, int d, int p1){
  __shared__ ushort_t lds[34816];
  uint32_t* h1[2] = { p.h1a, p.h1b };
  lin_body(p, lds, blockIdx.x, d, h1[1-p1]);
}

// ---- prep kernels ----
__global__ void bias_kernel(const float* a, const float* b, float* o){
  int i = blockIdx.x * 256 + threadIdx.x;
  if (i < 2048) o[i] = a[i] + b[i];
}

__global__ void prep_w(const float* __restrict__ Wih0, const float* __restrict__ Whh0,
                       const float* __restrict__ Wih1, const float* __restrict__ Whh1,
                       ushort_t* __restrict__ Wh, ushort_t* __restrict__ Wl)
{
  size_t i = (size_t)blockIdx.x*256 + threadIdx.x;
  if (i >= NTW) return;
  float val;
  if (i < N0W){
    int n   = (int)(i / W0TILE);
    int rem = (int)(i % W0TILE);
    int c   = rem / 8192;
    int rem2= rem & 8191;
    int cl  = rem2 >> 5;
    int q   = rem2 & 31;
    int k   = c*32 + q;
    int grow = ((cl>>4)&3)*512 + n*64 + ((cl>>6)&3)*16 + (cl&15);
    val = (k < 64) ? Wih0[(size_t)grow*64 + k] : Whh0[(size_t)grow*512 + (k-64)];
  } else {
    size_t e = i - N0W;
    int n   = (int)(e / W1TILE);
    int rem = (int)(e % W1TILE);
    int c   = rem / 8192;
    int rem2= rem & 8191;
    int cl  = rem2 >> 5;
    int q   = rem2 & 31;
    int k   = c*32 + q;
    int grow = ((cl>>4)&3)*512 + n*64 + ((cl>>6)&3)*16 + (cl&15);
    val = (k < 512) ? Wih1[(size_t)grow*512 + k] : Whh1[(size_t)grow*512 + (k-512)];
  }
  ushort_t h, lo2; split2(val, h, lo2);
  Wh[i] = h; Wl[i] = lo2;
}

extern "C" void kernel_launch(void* const* d_in, const int* in_sizes, int n_in,
                              void* d_out, int out_size, void* d_ws, size_t ws_size,
                              hipStream_t stream)
{
  const float* x     = (const float*)d_in[0];
  const float* W_ih0 = (const float*)d_in[1];
  const float* W_hh0 = (const float*)d_in[2];
  const float* b_ih0 = (const float*)d_in[3];
  const float* b_hh0 = (const float*)d_in[4];
  const float* W_ih1 = (const float*)d_in[5];
  const float* W_hh1 = (const float*)d_in[6];
  const float* b_ih1 = (const float*)d_in[7];
  const float* b_hh1 = (const float*)d_in[8];
  const float* W_lin = (const float*)d_in[9];
  const float* b_lin = (const float*)d_in[10];

  char* ws = (char*)d_ws;
  size_t off = 0;
  auto alloc = [&](size_t bytes){ size_t o = off; off += (bytes + 255) & ~(size_t)255; return o; };

  float* b0v = (float*)(ws + alloc(2048*4));
  float* b1v = (float*)(ws + alloc(2048*4));
  ushort_t* Wh = (ushort_t*)(ws + alloc(NTW*2));
  ushort_t* Wl = (ushort_t*)(ws + alloc(NTW*2));

  const size_t BH = (size_t)BSZ * HH;   // 262144
  size_t statesBytes = 4*BH*4 + 2*BH*4 + (size_t)BSZ*IIN*4 + 4096*4 + 512*4 + 16*4;
  char* states = ws + alloc(statesBytes);
  uint32_t* h0a = (uint32_t*)states;
  uint32_t* h0b = h0a + BH;
  uint32_t* h1a = h0a + 2*BH;
  uint32_t* h1b = h0a + 3*BH;
  float* c0m = (float*)(h0a + 4*BH);
  float* c1m = c0m + BH;
  uint32_t* outp = (uint32_t*)(c0m + 2*BH);
  uint32_t* bar  = outp + (size_t)BSZ*IIN;
  uint32_t* rel  = bar + 4096;
  uint32_t* assign = rel + 512;

  bias_kernel<<<8, 256, 0, stream>>>(b_ih0, b_hh0, b0v);
  bias_kernel<<<8, 256, 0, stream>>>(b_ih1, b_hh1, b1v);
  prep_w<<<(int)((NTW+255)/256), 256, 0, stream>>>(W_ih0, W_hh0, W_ih1, W_hh1, Wh, Wl);
  hipMemsetAsync(states, 0, statesBytes, stream);

  KP kp;
  kp.x = x; kp.Wh = Wh; kp.Wl = Wl; kp.b0v = b0v; kp.b1v = b1v;
  kp.Wlin = W_lin; kp.blin = b_lin;
  kp.h0a = h0a; kp.h0b = h0b; kp.h1a = h1a; kp.h1b = h1b;
  kp.c0m = c0m; kp.c1m = c1m; kp.outp = outp;
  kp.out = (float*)d_out;
  kp.bar = bar; kp.rel = rel; kp.assign = assign;

  void* kargs[] = { &kp };
  hipError_t ce = hipLaunchCooperativeKernel((void*)lstm_persist,
                                             dim3(NBLOCKS), dim3(256), kargs, 0, stream);
  if (ce != hipSuccess){
    for (int s = 0; s <= TT; ++s)
      fb_enc<<<NBLOCKS, 256, 0, stream>>>(kp, s);
    int p0 = 1, p1 = 1;
    for (int d = 0; d < NSTEPS; ++d){
      fb_dec0<<<NBLOCKS, 256, 0, stream>>>(kp, d, p0);
      fb_dec1<<<NBLOCKS, 256, 0, stream>>>(kp, p0, p1);
      fb_lin<<<32, 256, 0, stream>>>(kp, d, p1);
      p0 ^= 1; p1 ^= 1;
    }
  }
}

// Round 8
// 10576.448 us; speedup vs baseline: 3.2250x; 3.2250x over previous
//
#include <hip/hip_runtime.h>
#include <stdint.h>

#define BSZ 512
#define TT  256
#define IIN 64
#define HH  512
#define NSTEPS 10
#define NBLOCKS 512

typedef unsigned short ushort_t;
typedef short bf16x8 __attribute__((ext_vector_type(8)));
typedef float f32x4  __attribute__((ext_vector_type(4)));

static constexpr size_t W0TILE = 256*576;        // role0 per-n-tile elems
static constexpr size_t W1TILE = 256*1024;       // role1
static constexpr size_t N0W = 8*W0TILE;
static constexpr size_t NTW = N0W + 8*W1TILE;

__device__ __forceinline__ ushort_t f2bf(float f){
  union { float f; uint32_t u; } v; v.f = f;
  uint32_t u = v.u;
  return (ushort_t)((u + 0x7fffu + ((u >> 16) & 1u)) >> 16);
}
__device__ __forceinline__ float bf2f(ushort_t h){
  union { uint32_t u; float f; } v; v.u = ((uint32_t)h) << 16;
  return v.f;
}
__device__ __forceinline__ void split2(float f, ushort_t& h, ushort_t& l){
  h = f2bf(f); l = f2bf(f - bf2f(h));
}
__device__ __forceinline__ float sigf(float x){ return 1.0f/(1.0f+__expf(-x)); }
__device__ __forceinline__ float tanhfast(float x){ return 1.0f - 2.0f/(__expf(2.0f*x)+1.0f); }

__device__ __forceinline__ unsigned long long aload64(const uint32_t* p){
  return __hip_atomic_load((const unsigned long long*)(const void*)p,
                           __ATOMIC_RELAXED, __HIP_MEMORY_SCOPE_AGENT);
}
__device__ __forceinline__ void astore32(uint32_t* p, uint32_t v){
  __hip_atomic_store(p, v, __ATOMIC_RELAXED, __HIP_MEMORY_SCOPE_AGENT);
}
__device__ __forceinline__ uint32_t aload32(const uint32_t* p){
  return __hip_atomic_load(p, __ATOMIC_RELAXED, __HIP_MEMORY_SCOPE_AGENT);
}

__device__ __forceinline__ int get_xcd(){
  unsigned v;
  asm volatile("s_getreg_b32 %0, hwreg(HW_REG_XCC_ID)" : "=s"(v));
  return (int)(v & 7);
}

struct KP {
  const float* x;
  const ushort_t *Wh, *Wl;
  const float *b0v, *b1v;
  const float *Wlin, *blin;
  uint32_t *h0a, *h0b, *h1a, *h1b;   // packed h (hi | lo<<16) double buffers
  float *c0m, *c1m;                  // fallback c
  uint32_t *outp;
  float* out;
  uint32_t *bar, *rel, *assign;
};

// ---------------------------------------------------------------------------
// Cooperative weight-slice prefetch: block sweeps stripe m (of 32) of its
// n-slice with independent uint4 loads -> misses resolve at full HBM/MALL BW
// before the in-order MFMA B-stream consumes them. Values kept live via asm.
// ---------------------------------------------------------------------------
__device__ __forceinline__ void prefetch_w(const ushort_t* wh, const ushort_t* wl,
                                           size_t elems, int m){
  const size_t stripe = elems >> 5;                     // elems per m-stripe
  const uint4* ph = (const uint4*)(wh + (size_t)m*stripe);
  const uint4* pl = (const uint4*)(wl + (size_t)m*stripe);
  const int nu4 = (int)(stripe >> 3);
  uint32_t acc = 0;
  for (int i = threadIdx.x; i < nu4; i += 256){
    uint4 a = ph[i]; uint4 b = pl[i];
    acc ^= a.x ^ a.w ^ b.x ^ b.w;
  }
  asm volatile("" :: "v"(acc));
}

// LDS A layout: chunk c (32 k) x row r (0..15): 8 16B-units, XOR-swizzled.
__device__ __forceinline__ int lds_base(int c, int r){ return (c*16 + r)*64; }

__device__ __forceinline__ void stage_packed(ushort_t* lds, const uint32_t* src,
    int rowbase, int stride, int lognu, int cbase)
{
  const int nunits = 1 << lognu;
  const int ntasks = nunits << 4;
  for (int tsk = threadIdx.x; tsk < ntasks; tsk += 256){
    const int r  = tsk >> lognu;
    const int uk = tsk & (nunits-1);
    const uint32_t* sp = src + (size_t)(rowbase + r)*stride + uk*8;
    unsigned long long qq[4];
    qq[0]=aload64(sp); qq[1]=aload64(sp+2); qq[2]=aload64(sp+4); qq[3]=aload64(sp+6);
    union { ushort_t us[8]; bf16x8 v; } H, L;
    #pragma unroll
    for (int i2=0;i2<4;++i2){
      uint32_t a2 = (uint32_t)qq[i2], b2 = (uint32_t)(qq[i2]>>32);
      H.us[2*i2]   = (ushort_t)a2;  L.us[2*i2]   = (ushort_t)(a2>>16);
      H.us[2*i2+1] = (ushort_t)b2;  L.us[2*i2+1] = (ushort_t)(b2>>16);
    }
    const int c = cbase + (uk >> 2);
    const int u = uk & 3;
    const int sh = (u | ((c&1)<<2)) ^ (r&7);
    const int sl = (u | (((c&1)^1)<<2)) ^ (r&7);
    *(bf16x8*)&lds[lds_base(c,r) + sh*8] = H.v;
    *(bf16x8*)&lds[lds_base(c,r) + sl*8] = L.v;
  }
}

__device__ __forceinline__ void stage_f32(ushort_t* lds, const float* src,
    int rowbase, int stride, int cbase)   // always 64 k (8 units/row)
{
  const int tsk = threadIdx.x;
  if (tsk < 128){
    const int r = tsk >> 3, uk = tsk & 7;
    const float* sp = src + (size_t)(rowbase + r)*stride + uk*8;
    f32x4 v0 = *(const f32x4*)sp, v1 = *(const f32x4*)(sp+4);
    union { ushort_t us[8]; bf16x8 v; } H, L;
    #pragma unroll
    for (int i2=0;i2<4;++i2){
      split2(v0[i2], H.us[i2],   L.us[i2]);
      split2(v1[i2], H.us[4+i2], L.us[4+i2]);
    }
    const int c = cbase + (uk >> 2);
    const int u = uk & 3;
    const int sh = (u | ((c&1)<<2)) ^ (r&7);
    const int sl = (u | (((c&1)^1)<<2)) ^ (r&7);
    *(bf16x8*)&lds[lds_base(c,r) + sh*8] = H.v;
    *(bf16x8*)&lds[lds_base(c,r) + sl*8] = L.v;
  }
}

// ---------------------------------------------------------------------------
// Compute: block tile = 16 batch rows x 256 gate-cols (4 gates x 64 h-cols).
// Wave w owns h-cols [w*16, w*16+16) x all 4 gates. A from LDS, B from L2.
// Full K per wave -> no cross-wave reduction. Pointwise in-register.
// ---------------------------------------------------------------------------
__device__ __forceinline__ void cell_compute(const ushort_t* lds,
    const ushort_t* __restrict__ wh, const ushort_t* __restrict__ wl, int nch,
    int m, int n, const float* bias, float* c4, float* cmem, uint32_t* houtp)
{
  const int tid = threadIdx.x;
  const int w = tid >> 6, l = tid & 63;
  const int lr = l & 15, kq = l >> 4;
  f32x4 acc[4];
  #pragma unroll
  for (int s=0;s<4;++s) acc[s] = (f32x4){0.f,0.f,0.f,0.f};

  const int clb = w*64 + lr;
  for (int c = 0; c < nch; ++c){
    const int shi = (kq | ((c&1)<<2)) ^ (lr&7);
    const int slo = (kq | (((c&1)^1)<<2)) ^ (lr&7);
    bf16x8 ah = *(const bf16x8*)&lds[lds_base(c,lr) + shi*8];
    bf16x8 al = *(const bf16x8*)&lds[lds_base(c,lr) + slo*8];
    #pragma unroll
    for (int s=0;s<4;++s){
      size_t bo = ((size_t)(c*256 + clb + s*16))*32 + kq*8;
      bf16x8 bh = *(const bf16x8*)&wh[bo];
      bf16x8 bl = *(const bf16x8*)&wl[bo];
      acc[s] = __builtin_amdgcn_mfma_f32_16x16x32_bf16(ah, bh, acc[s],0,0,0);
      acc[s] = __builtin_amdgcn_mfma_f32_16x16x32_bf16(ah, bl, acc[s],0,0,0);
      acc[s] = __builtin_amdgcn_mfma_f32_16x16x32_bf16(al, bh, acc[s],0,0,0);
    }
  }

  const int j = n*64 + w*16 + lr;
  const float bi = bias[j], bf = bias[512+j], bg = bias[1024+j], bo2 = bias[1536+j];
  #pragma unroll
  for (int q=0;q<4;++q){
    const int row = m*16 + kq*4 + q;
    float gi = acc[0][q]+bi, gf = acc[1][q]+bf, gg = acc[2][q]+bg, go = acc[3][q]+bo2;
    const size_t cidx = ((size_t)row << 9) + j;
    float cold = cmem ? cmem[cidx] : c4[q];
    float cn = sigf(gf)*cold + sigf(gi)*tanhfast(gg);
    if (cmem) cmem[cidx] = cn; else c4[q] = cn;
    float hv = sigf(go)*tanhfast(cn);
    ushort_t hh2, hl2; split2(hv, hh2, hl2);
    astore32(&houtp[cidx], (uint32_t)hh2 | ((uint32_t)hl2 << 16));
  }
}

// ---- phase bodies ----
__device__ __forceinline__ void role0_step(const KP& p, ushort_t* lds, int m, int n,
    const float* xsrc, const uint32_t* osrc,
    const uint32_t* h0r, uint32_t* h0w, float* c4, float* cmem)
{
  prefetch_w(p.Wh + (size_t)n*W0TILE, p.Wl + (size_t)n*W0TILE, W0TILE, m);
  if (xsrc) stage_f32(lds, xsrc, m*16, TT*IIN, 0);
  else      stage_packed(lds, osrc, m*16, 64, 3, 0);
  stage_packed(lds, h0r, m*16, 512, 6, 2);
  __syncthreads();
  cell_compute(lds, p.Wh + (size_t)n*W0TILE, p.Wl + (size_t)n*W0TILE, 18,
               m, n, p.b0v, c4, cmem, h0w);
}

__device__ __forceinline__ void role1_step(const KP& p, ushort_t* lds, int m, int n,
    const uint32_t* h0cur, const uint32_t* h1r, uint32_t* h1w, float* c4, float* cmem)
{
  prefetch_w(p.Wh + N0W + (size_t)n*W1TILE, p.Wl + N0W + (size_t)n*W1TILE, W1TILE, m);
  stage_packed(lds, h0cur, m*16, 512, 6, 0);
  stage_packed(lds, h1r,   m*16, 512, 6, 16);
  __syncthreads();
  cell_compute(lds, p.Wh + N0W + (size_t)n*W1TILE, p.Wl + N0W + (size_t)n*W1TILE, 32,
               m, n, p.b1v, c4, cmem, h1w);
}

__device__ __forceinline__ void lin_step(const KP& p, ushort_t* lds, int m, int d,
                                         const uint32_t* h1cur)
{
  float* lf = (float*)lds;                 // [16][512] f32 = 32 KB
  const int r0 = m*16;
  for (int tsk = threadIdx.x; tsk < 4096; tsk += 256){
    const int r = tsk >> 8, e2 = (tsk & 255)*2;
    unsigned long long q = aload64(h1cur + (size_t)(r0+r)*512 + e2);
    uint32_t a2 = (uint32_t)q, b2 = (uint32_t)(q>>32);
    lf[r*512 + e2]     = bf2f((ushort_t)a2) + bf2f((ushort_t)(a2>>16));
    lf[r*512 + e2 + 1] = bf2f((ushort_t)b2) + bf2f((ushort_t)(b2>>16));
  }
  __syncthreads();
  const int i = threadIdx.x & 63;
  const int rq = threadIdx.x >> 6;
  const float* wr = p.Wlin + (size_t)i*512;
  float sum[4] = {0.f,0.f,0.f,0.f};
  for (int k = 0; k < 512; k += 4){
    f32x4 wv = *(const f32x4*)(wr + k);
    #pragma unroll
    for (int q2=0;q2<4;++q2){
      const float* hfp = &lf[(rq*4+q2)*512 + k];
      sum[q2] += hfp[0]*wv[0] + hfp[1]*wv[1] + hfp[2]*wv[2] + hfp[3]*wv[3];
    }
  }
  #pragma unroll
  for (int q2=0;q2<4;++q2){
    const int row = r0 + rq*4 + q2;
    float v = sum[q2] + p.blin[i];
    p.out[(size_t)row*(NSTEPS*IIN) + d*IIN + i] = v;
    ushort_t oh, ol; split2(v, oh, ol);
    astore32(&p.outp[row*64 + i], (uint32_t)oh | ((uint32_t)ol<<16));
  }
  __syncthreads();
}

// ---- persistent kernel: XCD-ticket tile assignment + flag grid barrier ----
__global__ __launch_bounds__(256, 2)
void lstm_persist(KP p)
{
  __shared__ ushort_t lds[32768];   // 64 KB
  __shared__ int s_lt;
  if (threadIdx.x == 0){
    const int xcd = get_xcd();
    int lt = 0;
    for (int a = 0; a < 8; ++a){
      const int xx = (xcd + a) & 7;
      uint32_t idx = __hip_atomic_fetch_add(&p.assign[xx], 1u, __ATOMIC_RELAXED,
                                            __HIP_MEMORY_SCOPE_AGENT);
      if (idx < 64u){ lt = xx*64 + (int)idx; break; }
    }
    s_lt = lt;
  }
  __syncthreads();
  const int lt = s_lt;
  const int n = lt >> 6;           // n == XCD -> weight slice L2-affine
  const int li = lt & 63;
  const int role = li >> 5;
  const int m = li & 31;

  float c4[4] = {0.f,0.f,0.f,0.f};
  uint32_t* h0[2] = { p.h0a, p.h0b };
  uint32_t* h1[2] = { p.h1a, p.h1b };

  int slot = 0;
  auto gbar = [&](){
    __syncthreads();
    if (threadIdx.x == 0){
      uint32_t old = __hip_atomic_fetch_add(&p.bar[slot], 1u, __ATOMIC_RELAXED,
                                            __HIP_MEMORY_SCOPE_AGENT);
      if (old == (uint32_t)(NBLOCKS-1)){
        __hip_atomic_store(&p.rel[slot], 1u, __ATOMIC_RELAXED, __HIP_MEMORY_SCOPE_AGENT);
      } else {
        while (!aload32(&p.rel[slot])) __builtin_amdgcn_s_sleep(1);
      }
    }
    __syncthreads();
    ++slot;
  };

  for (int s = 0; s <= TT; ++s){
    if (role == 0 && s < TT){
      role0_step(p, lds, m, n, p.x + (size_t)s*IIN, nullptr,
                 h0[(s+1)&1], h0[s&1], c4, nullptr);
    } else if (role == 1 && s >= 1){
      const int t = s-1;
      role1_step(p, lds, m, n, h0[t&1], h1[(t+1)&1], h1[t&1], c4, nullptr);
    }
    gbar();
  }
  int p0 = 1, p1 = 1;
  for (int d = 0; d < NSTEPS; ++d){
    if (role == 0){
      if (d == 0) role0_step(p, lds, m, n, p.x + (size_t)(TT-1)*IIN, nullptr,
                             h0[p0], h0[1-p0], c4, nullptr);
      else        role0_step(p, lds, m, n, nullptr, p.outp,
                             h0[p0], h0[1-p0], c4, nullptr);
    }
    gbar();
    if (role == 1) role1_step(p, lds, m, n, h0[1-p0], h1[p1], h1[1-p1], c4, nullptr);
    gbar();
    if (role == 0 && n == 0) lin_step(p, lds, m, d, h1[1-p1]);
    gbar();
    p0 ^= 1; p1 ^= 1;
  }
}

// ---- fallback per-step kernels (static tiles, c in global) ----
__global__ __launch_bounds__(256, 2)
void fb_enc(KP p, int s){
  __shared__ ushort_t lds[32768];
  uint32_t* h0[2] = { p.h0a, p.h0b };
  uint32_t* h1[2] = { p.h1a, p.h1b };
  const int bid = blockIdx.x;
  const int role = bid >> 8, tile = bid & 255, m = tile >> 3, n = tile & 7;
  if (role == 0 && s < TT)
    role0_step(p, lds, m, n, p.x + (size_t)s*IIN, nullptr,
               h0[(s+1)&1], h0[s&1], nullptr, p.c0m);
  else if (role == 1 && s >= 1){
    const int t = s-1;
    role1_step(p, lds, m, n, h0[t&1], h1[(t+1)&1], h1[t&1], nullptr, p.c1m);
  }
}
__global__ __launch_bounds__(256, 2)
void fb_dec0(KP p, int d, int p0){
  __shared__ ushort_t lds[32768];
  uint32_t* h0[2] = { p.h0a, p.h0b };
  const int m = blockIdx.x >> 3, n = blockIdx.x & 7;
  if (d == 0) role0_step(p, lds, m, n, p.x + (size_t)(TT-1)*IIN, nullptr,
                         h0[p0], h0[1-p0], nullptr, p.c0m);
  else        role0_step(p, lds, m, n, nullptr, p.outp,
                         h0[p0], h0[1-p0], nullptr, p.c0m);
}
__global__ __launch_bounds__(256, 2)
void fb_dec1(KP p, int p0, int p1){
  __shared__ ushort_t lds[32768];
  uint32_t* h0[2] = { p.h0a, p.h0b };
  uint32_t* h1[2] = { p.h1a, p.h1b };
  const int m = blockIdx.x >> 3, n = blockIdx.x & 7;
  role1_step(p, lds, m, n, h0[1-p0], h1[p1], h1[1-p1], nullptr, p.c1m);
}
__global__ __launch_bounds__(256)
void fb_lin(KP p, int d, int p1){
  __shared__ ushort_t lds[32768];
  uint32_t* h1[2] = { p.h1a, p.h1b };
  lin_step(p, lds, blockIdx.x, d, h1[1-p1]);
}

// ---- prep kernels ----
__global__ void bias_kernel(const float* a, const float* b, float* o){
  int i = blockIdx.x * 256 + threadIdx.x;
  if (i < 2048) o[i] = a[i] + b[i];
}

__global__ void prep_w(const float* __restrict__ Wih0, const float* __restrict__ Whh0,
                       const float* __restrict__ Wih1, const float* __restrict__ Whh1,
                       ushort_t* __restrict__ Wh, ushort_t* __restrict__ Wl)
{
  size_t i = (size_t)blockIdx.x*256 + threadIdx.x;
  if (i >= NTW) return;
  float val;
  if (i < N0W){
    int n   = (int)(i / W0TILE);
    int rem = (int)(i % W0TILE);
    int c   = rem / 8192;
    int rem2= rem & 8191;
    int cl  = rem2 >> 5;
    int q   = rem2 & 31;
    int k   = c*32 + q;
    int grow = ((cl>>4)&3)*512 + n*64 + ((cl>>6)&3)*16 + (cl&15);
    val = (k < 64) ? Wih0[(size_t)grow*64 + k] : Whh0[(size_t)grow*512 + (k-64)];
  } else {
    size_t e = i - N0W;
    int n   = (int)(e / W1TILE);
    int rem = (int)(e % W1TILE);
    int c   = rem / 8192;
    int rem2= rem & 8191;
    int cl  = rem2 >> 5;
    int q   = rem2 & 31;
    int k   = c*32 + q;
    int grow = ((cl>>4)&3)*512 + n*64 + ((cl>>6)&3)*16 + (cl&15);
    val = (k < 512) ? Wih1[(size_t)grow*512 + k] : Whh1[(size_t)grow*512 + (k-512)];
  }
  ushort_t h, lo2; split2(val, h, lo2);
  Wh[i] = h; Wl[i] = lo2;
}

extern "C" void kernel_launch(void* const* d_in, const int* in_sizes, int n_in,
                              void* d_out, int out_size, void* d_ws, size_t ws_size,
                              hipStream_t stream)
{
  const float* x     = (const float*)d_in[0];
  const float* W_ih0 = (const float*)d_in[1];
  const float* W_hh0 = (const float*)d_in[2];
  const float* b_ih0 = (const float*)d_in[3];
  const float* b_hh0 = (const float*)d_in[4];
  const float* W_ih1 = (const float*)d_in[5];
  const float* W_hh1 = (const float*)d_in[6];
  const float* b_ih1 = (const float*)d_in[7];
  const float* b_hh1 = (const float*)d_in[8];
  const float* W_lin = (const float*)d_in[9];
  const float* b_lin = (const float*)d_in[10];

  char* ws = (char*)d_ws;
  size_t off = 0;
  auto alloc = [&](size_t bytes){ size_t o = off; off += (bytes + 255) & ~(size_t)255; return o; };

  float* b0v = (float*)(ws + alloc(2048*4));
  float* b1v = (float*)(ws + alloc(2048*4));
  ushort_t* Wh = (ushort_t*)(ws + alloc(NTW*2));
  ushort_t* Wl = (ushort_t*)(ws + alloc(NTW*2));

  const size_t BH = (size_t)BSZ * HH;   // 262144
  size_t statesBytes = 4*BH*4 + 2*BH*4 + (size_t)BSZ*IIN*4 + 512*4 + 512*4 + 16*4;
  char* states = ws + alloc(statesBytes);
  uint32_t* h0a = (uint32_t*)states;
  uint32_t* h0b = h0a + BH;
  uint32_t* h1a = h0a + 2*BH;
  uint32_t* h1b = h0a + 3*BH;
  float* c0m = (float*)(h0a + 4*BH);
  float* c1m = c0m + BH;
  uint32_t* outp = (uint32_t*)(c0m + 2*BH);
  uint32_t* bar  = outp + (size_t)BSZ*IIN;
  uint32_t* rel  = bar + 512;
  uint32_t* assign = rel + 512;

  bias_kernel<<<8, 256, 0, stream>>>(b_ih0, b_hh0, b0v);
  bias_kernel<<<8, 256, 0, stream>>>(b_ih1, b_hh1, b1v);
  prep_w<<<(int)((NTW+255)/256), 256, 0, stream>>>(W_ih0, W_hh0, W_ih1, W_hh1, Wh, Wl);
  hipMemsetAsync(states, 0, statesBytes, stream);

  KP kp;
  kp.x = x; kp.Wh = Wh; kp.Wl = Wl; kp.b0v = b0v; kp.b1v = b1v;
  kp.Wlin = W_lin; kp.blin = b_lin;
  kp.h0a = h0a; kp.h0b = h0b; kp.h1a = h1a; kp.h1b = h1b;
  kp.c0m = c0m; kp.c1m = c1m; kp.outp = outp;
  kp.out = (float*)d_out;
  kp.bar = bar; kp.rel = rel; kp.assign = assign;

  void* kargs[] = { &kp };
  hipError_t ce = hipLaunchCooperativeKernel((void*)lstm_persist,
                                             dim3(NBLOCKS), dim3(256), kargs, 0, stream);
  if (ce != hipSuccess){
    for (int s = 0; s <= TT; ++s)
      fb_enc<<<NBLOCKS, 256, 0, stream>>>(kp, s);
    int p0 = 1, p1 = 1;
    for (int d = 0; d < NSTEPS; ++d){
      fb_dec0<<<256, 256, 0, stream>>>(kp, d, p0);
      fb_dec1<<<256, 256, 0, stream>>>(kp, p0, p1);
      fb_lin<<<32, 256, 0, stream>>>(kp, d, p1);
      p0 ^= 1; p1 ^= 1;
    }
  }
}

// Round 9
// 9940.728 us; speedup vs baseline: 3.4313x; 1.0640x over previous
//
#include <hip/hip_runtime.h>
#include <stdint.h>

#define BSZ 512
#define TT  256
#define IIN 64
#define HH  512
#define NSTEPS 10
#define NBLOCKS 512

typedef unsigned short ushort_t;
typedef short bf16x8 __attribute__((ext_vector_type(8)));
typedef float f32x4  __attribute__((ext_vector_type(4)));

static constexpr size_t W0TILE = 256*576;        // role0 per-n-tile elems
static constexpr size_t W1TILE = 256*1024;       // role1
static constexpr size_t N0W = 8*W0TILE;
static constexpr size_t NTW = N0W + 8*W1TILE;

__device__ __forceinline__ ushort_t f2bf(float f){
  union { float f; uint32_t u; } v; v.f = f;
  uint32_t u = v.u;
  return (ushort_t)((u + 0x7fffu + ((u >> 16) & 1u)) >> 16);
}
__device__ __forceinline__ float bf2f(ushort_t h){
  union { uint32_t u; float f; } v; v.u = ((uint32_t)h) << 16;
  return v.f;
}
__device__ __forceinline__ void split2(float f, ushort_t& h, ushort_t& l){
  h = f2bf(f); l = f2bf(f - bf2f(h));
}
__device__ __forceinline__ float sigf(float x){ return 1.0f/(1.0f+__expf(-x)); }
__device__ __forceinline__ float tanhfast(float x){ return 1.0f - 2.0f/(__expf(2.0f*x)+1.0f); }

__device__ __forceinline__ unsigned long long aload64(const uint32_t* p){
  return __hip_atomic_load((const unsigned long long*)(const void*)p,
                           __ATOMIC_RELAXED, __HIP_MEMORY_SCOPE_AGENT);
}
__device__ __forceinline__ void astore32(uint32_t* p, uint32_t v){
  __hip_atomic_store(p, v, __ATOMIC_RELAXED, __HIP_MEMORY_SCOPE_AGENT);
}
__device__ __forceinline__ uint32_t aload32(const uint32_t* p){
  return __hip_atomic_load(p, __ATOMIC_RELAXED, __HIP_MEMORY_SCOPE_AGENT);
}

__device__ __forceinline__ int get_xcd(){
  unsigned v;
  asm volatile("s_getreg_b32 %0, hwreg(HW_REG_XCC_ID)" : "=s"(v));
  return (int)(v & 7);
}

struct KP {
  const float* x;
  const ushort_t *Wh, *Wl;
  const float *b0v, *b1v;
  const float *Wlin, *blin;
  uint32_t *h0a, *h0b, *h1a, *h1b;   // packed h (hi | lo<<16) double buffers
  float *c0m, *c1m;                  // fallback c
  uint32_t *outp;
  float* out;
  uint32_t *bar, *rel, *assign;
};

// LDS A layout: chunk c (32 k) x row r (0..15): 8 16B-units, XOR-swizzled.
__device__ __forceinline__ int lds_base(int c, int r){ return (c*16 + r)*64; }

// ---- issue-first staging of packed h (NU 8-elem units per row, 16 rows) ----
template<int NU>
struct StageP {
  static constexpr int NTASK = NU*16;
  static constexpr int TPT = (NTASK + 255)/256;
  unsigned long long q[TPT][4];
  __device__ __forceinline__ void issue(const uint32_t* src, int rowbase, int stride){
    #pragma unroll
    for (int i=0;i<TPT;++i){
      const int t = i*256 + (int)threadIdx.x;
      if (NTASK % 256 == 0 || t < NTASK){
        const int r = t / NU, uk = t - r*NU;
        const uint32_t* sp = src + (size_t)(rowbase+r)*stride + uk*8;
        q[i][0]=aload64(sp);   q[i][1]=aload64(sp+2);
        q[i][2]=aload64(sp+4); q[i][3]=aload64(sp+6);
      }
    }
  }
  __device__ __forceinline__ void commit(ushort_t* lds, int cbase){
    #pragma unroll
    for (int i=0;i<TPT;++i){
      const int t = i*256 + (int)threadIdx.x;
      if (NTASK % 256 == 0 || t < NTASK){
        const int r = t / NU, uk = t - r*NU;
        union { ushort_t us[8]; bf16x8 v; } H, L;
        #pragma unroll
        for (int j=0;j<4;++j){
          uint32_t a2=(uint32_t)q[i][j], b2=(uint32_t)(q[i][j]>>32);
          H.us[2*j]  =(ushort_t)a2; L.us[2*j]  =(ushort_t)(a2>>16);
          H.us[2*j+1]=(ushort_t)b2; L.us[2*j+1]=(ushort_t)(b2>>16);
        }
        const int c = cbase + (uk>>2), u = uk&3;
        const int sh = (u | ((c&1)<<2)) ^ (r&7);
        const int sl = (u | (((c&1)^1)<<2)) ^ (r&7);
        *(bf16x8*)&lds[lds_base(c,r)+sh*8] = H.v;
        *(bf16x8*)&lds[lds_base(c,r)+sl*8] = L.v;
      }
    }
  }
};

// f32 x staging: 16 rows x 64 k -> chunks cbase..cbase+1 (plain cached loads)
struct StageF {
  f32x4 v0, v1;
  __device__ __forceinline__ void issue(const float* src, int rowbase, int stride){
    const int t = threadIdx.x;
    if (t < 128){
      const int r = t>>3, uk = t&7;
      const float* sp = src + (size_t)(rowbase+r)*stride + uk*8;
      v0 = *(const f32x4*)sp; v1 = *(const f32x4*)(sp+4);
    }
  }
  __device__ __forceinline__ void commit(ushort_t* lds, int cbase){
    const int t = threadIdx.x;
    if (t < 128){
      const int r = t>>3, uk = t&7;
      union { ushort_t us[8]; bf16x8 v; } H, L;
      #pragma unroll
      for (int j=0;j<4;++j){
        split2(v0[j], H.us[j],   L.us[j]);
        split2(v1[j], H.us[4+j], L.us[4+j]);
      }
      const int c = cbase + (uk>>2), u = uk&3;
      const int sh = (u | ((c&1)<<2)) ^ (r&7);
      const int sl = (u | (((c&1)^1)<<2)) ^ (r&7);
      *(bf16x8*)&lds[lds_base(c,r)+sh*8] = H.v;
      *(bf16x8*)&lds[lds_base(c,r)+sl*8] = L.v;
    }
  }
};

// ---------------------------------------------------------------------------
// Compute: block tile = 16 batch rows x 256 gate-cols (4 gates x 64 h-cols).
// Wave w owns h-cols [w*16, w*16+16) x all 4 gates. A from LDS, B from L2.
// Full K per wave -> no cross-wave reduction. Pointwise in-register.
// ---------------------------------------------------------------------------
__device__ __forceinline__ void cell_compute(const ushort_t* lds,
    const ushort_t* __restrict__ wh, const ushort_t* __restrict__ wl, int nch,
    int m, int n, const float* bias, float* c4, float* cmem, uint32_t* houtp)
{
  const int tid = threadIdx.x;
  const int w = tid >> 6, l = tid & 63;
  const int lr = l & 15, kq = l >> 4;
  f32x4 acc[4];
  #pragma unroll
  for (int s=0;s<4;++s) acc[s] = (f32x4){0.f,0.f,0.f,0.f};

  const int clb = w*64 + lr;
  for (int c = 0; c < nch; ++c){
    const int shi = (kq | ((c&1)<<2)) ^ (lr&7);
    const int slo = (kq | (((c&1)^1)<<2)) ^ (lr&7);
    bf16x8 ah = *(const bf16x8*)&lds[lds_base(c,lr) + shi*8];
    bf16x8 al = *(const bf16x8*)&lds[lds_base(c,lr) + slo*8];
    #pragma unroll
    for (int s=0;s<4;++s){
      size_t bo = ((size_t)(c*256 + clb + s*16))*32 + kq*8;
      bf16x8 bh = *(const bf16x8*)&wh[bo];
      bf16x8 bl = *(const bf16x8*)&wl[bo];
      acc[s] = __builtin_amdgcn_mfma_f32_16x16x32_bf16(ah, bh, acc[s],0,0,0);
      acc[s] = __builtin_amdgcn_mfma_f32_16x16x32_bf16(ah, bl, acc[s],0,0,0);
      acc[s] = __builtin_amdgcn_mfma_f32_16x16x32_bf16(al, bh, acc[s],0,0,0);
    }
  }

  const int j = n*64 + w*16 + lr;
  const float bi = bias[j], bf = bias[512+j], bg = bias[1024+j], bo2 = bias[1536+j];
  #pragma unroll
  for (int q=0;q<4;++q){
    const int row = m*16 + kq*4 + q;
    float gi = acc[0][q]+bi, gf = acc[1][q]+bf, gg = acc[2][q]+bg, go = acc[3][q]+bo2;
    const size_t cidx = ((size_t)row << 9) + j;
    float cold = cmem ? cmem[cidx] : c4[q];
    float cn = sigf(gf)*cold + sigf(gi)*tanhfast(gg);
    if (cmem) cmem[cidx] = cn; else c4[q] = cn;
    float hv = sigf(go)*tanhfast(cn);
    ushort_t hh2, hl2; split2(hv, hh2, hl2);
    astore32(&houtp[cidx], (uint32_t)hh2 | ((uint32_t)hl2 << 16));
  }
}

// ---- phase bodies (issue-first staging) ----
__device__ __forceinline__ void role0_step(const KP& p, ushort_t* lds, int m, int n,
    const float* xsrc, const uint32_t* osrc,
    const uint32_t* h0r, uint32_t* h0w, float* c4, float* cmem)
{
  StageF SX; StageP<8> SO; StageP<64> S0;
  if (xsrc) SX.issue(xsrc, m*16, TT*IIN);
  else      SO.issue(osrc, m*16, 64);
  S0.issue(h0r, m*16, 512);
  if (xsrc) SX.commit(lds, 0); else SO.commit(lds, 0);
  S0.commit(lds, 2);
  __syncthreads();
  cell_compute(lds, p.Wh + (size_t)n*W0TILE, p.Wl + (size_t)n*W0TILE, 18,
               m, n, p.b0v, c4, cmem, h0w);
}

__device__ __forceinline__ void role1_step(const KP& p, ushort_t* lds, int m, int n,
    const uint32_t* h0cur, const uint32_t* h1r, uint32_t* h1w, float* c4, float* cmem)
{
  StageP<64> SA; StageP<64> SB;
  SA.issue(h0cur, m*16, 512);
  SB.issue(h1r,   m*16, 512);
  SA.commit(lds, 0);
  SB.commit(lds, 16);
  __syncthreads();
  cell_compute(lds, p.Wh + N0W + (size_t)n*W1TILE, p.Wl + N0W + (size_t)n*W1TILE, 32,
               m, n, p.b1v, c4, cmem, h1w);
}

__device__ __forceinline__ void lin_step(const KP& p, ushort_t* lds, int m, int d,
                                         const uint32_t* h1cur)
{
  float* lf = (float*)lds;                 // [16][512] f32 = 32 KB
  const int r0 = m*16;
  for (int tsk = threadIdx.x; tsk < 4096; tsk += 256){
    const int r = tsk >> 8, e2 = (tsk & 255)*2;
    unsigned long long q = aload64(h1cur + (size_t)(r0+r)*512 + e2);
    uint32_t a2 = (uint32_t)q, b2 = (uint32_t)(q>>32);
    lf[r*512 + e2]     = bf2f((ushort_t)a2) + bf2f((ushort_t)(a2>>16));
    lf[r*512 + e2 + 1] = bf2f((ushort_t)b2) + bf2f((ushort_t)(b2>>16));
  }
  __syncthreads();
  const int i = threadIdx.x & 63;
  const int rq = threadIdx.x >> 6;
  const float* wr = p.Wlin + (size_t)i*512;
  float sum[4] = {0.f,0.f,0.f,0.f};
  for (int k = 0; k < 512; k += 4){
    f32x4 wv = *(const f32x4*)(wr + k);
    #pragma unroll
    for (int q2=0;q2<4;++q2){
      const float* hfp = &lf[(rq*4+q2)*512 + k];
      sum[q2] += hfp[0]*wv[0] + hfp[1]*wv[1] + hfp[2]*wv[2] + hfp[3]*wv[3];
    }
  }
  #pragma unroll
  for (int q2=0;q2<4;++q2){
    const int row = r0 + rq*4 + q2;
    float v = sum[q2] + p.blin[i];
    p.out[(size_t)row*(NSTEPS*IIN) + d*IIN + i] = v;
    ushort_t oh, ol; split2(v, oh, ol);
    astore32(&p.outp[row*64 + i], (uint32_t)oh | ((uint32_t)ol<<16));
  }
  __syncthreads();
}

// ---- persistent kernel: XCD-ticket + PER-M-GROUP monotonic barrier ----
// After prep, the computation partitions exactly by batch-row group m:
// h0/h1/outp/c/out are row-sliced, x & W read-only. Each group of 16 blocks
// {role0(m,n=0..7), role1(m,n=0..7)} syncs only among itself.
__global__ __launch_bounds__(256, 2)
void lstm_persist(KP p)
{
  __shared__ ushort_t lds[32768];   // 64 KB
  __shared__ int s_lt;
  if (threadIdx.x == 0){
    const int xcd = get_xcd();
    int lt = 0;
    for (int a = 0; a < 8; ++a){
      const int xx = (xcd + a) & 7;
      uint32_t idx = __hip_atomic_fetch_add(&p.assign[xx], 1u, __ATOMIC_RELAXED,
                                            __HIP_MEMORY_SCOPE_AGENT);
      if (idx < 64u){ lt = xx*64 + (int)idx; break; }
    }
    s_lt = lt;
  }
  __syncthreads();
  const int lt = s_lt;
  const int n = lt >> 6;           // n == XCD -> weight slice L2-affine
  const int li = lt & 63;
  const int role = li >> 5;
  const int m = li & 31;

  float c4[4] = {0.f,0.f,0.f,0.f};
  uint32_t* h0[2] = { p.h0a, p.h0b };
  uint32_t* h1[2] = { p.h1a, p.h1b };

  uint32_t* grpline = &p.bar[m*16];   // 64B-separated line per m-group
  uint32_t target = 0;
  auto gbar = [&](){
    __syncthreads();                  // drains this block's stores
    if (threadIdx.x == 0){
      target += 16;
      __hip_atomic_fetch_add(grpline, 1u, __ATOMIC_RELAXED, __HIP_MEMORY_SCOPE_AGENT);
      while (aload32(grpline) < target) __builtin_amdgcn_s_sleep(1);
    }
    __syncthreads();
  };

  for (int s = 0; s <= TT; ++s){
    if (role == 0 && s < TT){
      role0_step(p, lds, m, n, p.x + (size_t)s*IIN, nullptr,
                 h0[(s+1)&1], h0[s&1], c4, nullptr);
    } else if (role == 1 && s >= 1){
      const int t = s-1;
      role1_step(p, lds, m, n, h0[t&1], h1[(t+1)&1], h1[t&1], c4, nullptr);
    }
    gbar();
  }
  int p0 = 1, p1 = 1;
  for (int d = 0; d < NSTEPS; ++d){
    if (role == 0){
      if (d == 0) role0_step(p, lds, m, n, p.x + (size_t)(TT-1)*IIN, nullptr,
                             h0[p0], h0[1-p0], c4, nullptr);
      else        role0_step(p, lds, m, n, nullptr, p.outp,
                             h0[p0], h0[1-p0], c4, nullptr);
    }
    gbar();
    if (role == 1) role1_step(p, lds, m, n, h0[1-p0], h1[p1], h1[1-p1], c4, nullptr);
    gbar();
    if (role == 0 && n == 0) lin_step(p, lds, m, d, h1[1-p1]);
    gbar();
    p0 ^= 1; p1 ^= 1;
  }
}

// ---- fallback per-step kernels (static tiles, c in global) ----
__global__ __launch_bounds__(256, 2)
void fb_enc(KP p, int s){
  __shared__ ushort_t lds[32768];
  uint32_t* h0[2] = { p.h0a, p.h0b };
  uint32_t* h1[2] = { p.h1a, p.h1b };
  const int bid = blockIdx.x;
  const int role = bid >> 8, tile = bid & 255, m = tile >> 3, n = tile & 7;
  if (role == 0 && s < TT)
    role0_step(p, lds, m, n, p.x + (size_t)s*IIN, nullptr,
               h0[(s+1)&1], h0[s&1], nullptr, p.c0m);
  else if (role == 1 && s >= 1){
    const int t = s-1;
    role1_step(p, lds, m, n, h0[t&1], h1[(t+1)&1], h1[t&1], nullptr, p.c1m);
  }
}
__global__ __launch_bounds__(256, 2)
void fb_dec0(KP p, int d, int p0){
  __shared__ ushort_t lds[32768];
  uint32_t* h0[2] = { p.h0a, p.h0b };
  const int m = blockIdx.x >> 3, n = blockIdx.x & 7;
  if (d == 0) role0_step(p, lds, m, n, p.x + (size_t)(TT-1)*IIN, nullptr,
                         h0[p0], h0[1-p0], nullptr, p.c0m);
  else        role0_step(p, lds, m, n, nullptr, p.outp,
                         h0[p0], h0[1-p0], nullptr, p.c0m);
}
__global__ __launch_bounds__(256, 2)
void fb_dec1(KP p, int p0, int p1){
  __shared__ ushort_t lds[32768];
  uint32_t* h0[2] = { p.h0a, p.h0b };
  uint32_t* h1[2] = { p.h1a, p.h1b };
  const int m = blockIdx.x >> 3, n = blockIdx.x & 7;
  role1_step(p, lds, m, n, h0[1-p0], h1[p1], h1[1-p1], nullptr, p.c1m);
}
__global__ __launch_bounds__(256)
void fb_lin(KP p, int d, int p1){
  __shared__ ushort_t lds[32768];
  uint32_t* h1[2] = { p.h1a, p.h1b };
  lin_step(p, lds, blockIdx.x, d, h1[1-p1]);
}

// ---- prep kernels ----
__global__ void bias_kernel(const float* a, const float* b, float* o){
  int i = blockIdx.x * 256 + threadIdx.x;
  if (i < 2048) o[i] = a[i] + b[i];
}

__global__ void prep_w(const float* __restrict__ Wih0, const float* __restrict__ Whh0,
                       const float* __restrict__ Wih1, const float* __restrict__ Whh1,
                       ushort_t* __restrict__ Wh, ushort_t* __restrict__ Wl)
{
  size_t i = (size_t)blockIdx.x*256 + threadIdx.x;
  if (i >= NTW) return;
  float val;
  if (i < N0W){
    int n   = (int)(i / W0TILE);
    int rem = (int)(i % W0TILE);
    int c   = rem / 8192;
    int rem2= rem & 8191;
    int cl  = rem2 >> 5;
    int q   = rem2 & 31;
    int k   = c*32 + q;
    int grow = ((cl>>4)&3)*512 + n*64 + ((cl>>6)&3)*16 + (cl&15);
    val = (k < 64) ? Wih0[(size_t)grow*64 + k] : Whh0[(size_t)grow*512 + (k-64)];
  } else {
    size_t e = i - N0W;
    int n   = (int)(e / W1TILE);
    int rem = (int)(e % W1TILE);
    int c   = rem / 8192;
    int rem2= rem & 8191;
    int cl  = rem2 >> 5;
    int q   = rem2 & 31;
    int k   = c*32 + q;
    int grow = ((cl>>4)&3)*512 + n*64 + ((cl>>6)&3)*16 + (cl&15);
    val = (k < 512) ? Wih1[(size_t)grow*512 + k] : Whh1[(size_t)grow*512 + (k-512)];
  }
  ushort_t h, lo2; split2(val, h, lo2);
  Wh[i] = h; Wl[i] = lo2;
}

extern "C" void kernel_launch(void* const* d_in, const int* in_sizes, int n_in,
                              void* d_out, int out_size, void* d_ws, size_t ws_size,
                              hipStream_t stream)
{
  const float* x     = (const float*)d_in[0];
  const float* W_ih0 = (const float*)d_in[1];
  const float* W_hh0 = (const float*)d_in[2];
  const float* b_ih0 = (const float*)d_in[3];
  const float* b_hh0 = (const float*)d_in[4];
  const float* W_ih1 = (const float*)d_in[5];
  const float* W_hh1 = (const float*)d_in[6];
  const float* b_ih1 = (const float*)d_in[7];
  const float* b_hh1 = (const float*)d_in[8];
  const float* W_lin = (const float*)d_in[9];
  const float* b_lin = (const float*)d_in[10];

  char* ws = (char*)d_ws;
  size_t off = 0;
  auto alloc = [&](size_t bytes){ size_t o = off; off += (bytes + 255) & ~(size_t)255; return o; };

  float* b0v = (float*)(ws + alloc(2048*4));
  float* b1v = (float*)(ws + alloc(2048*4));
  ushort_t* Wh = (ushort_t*)(ws + alloc(NTW*2));
  ushort_t* Wl = (ushort_t*)(ws + alloc(NTW*2));

  const size_t BH = (size_t)BSZ * HH;   // 262144
  size_t statesBytes = 4*BH*4 + 2*BH*4 + (size_t)BSZ*IIN*4 + 512*4 + 512*4 + 16*4;
  char* states = ws + alloc(statesBytes);
  uint32_t* h0a = (uint32_t*)states;
  uint32_t* h0b = h0a + BH;
  uint32_t* h1a = h0a + 2*BH;
  uint32_t* h1b = h0a + 3*BH;
  float* c0m = (float*)(h0a + 4*BH);
  float* c1m = c0m + BH;
  uint32_t* outp = (uint32_t*)(c0m + 2*BH);
  uint32_t* bar  = outp + (size_t)BSZ*IIN;
  uint32_t* rel  = bar + 512;
  uint32_t* assign = rel + 512;

  bias_kernel<<<8, 256, 0, stream>>>(b_ih0, b_hh0, b0v);
  bias_kernel<<<8, 256, 0, stream>>>(b_ih1, b_hh1, b1v);
  prep_w<<<(int)((NTW+255)/256), 256, 0, stream>>>(W_ih0, W_hh0, W_ih1, W_hh1, Wh, Wl);
  hipMemsetAsync(states, 0, statesBytes, stream);

  KP kp;
  kp.x = x; kp.Wh = Wh; kp.Wl = Wl; kp.b0v = b0v; kp.b1v = b1v;
  kp.Wlin = W_lin; kp.blin = b_lin;
  kp.h0a = h0a; kp.h0b = h0b; kp.h1a = h1a; kp.h1b = h1b;
  kp.c0m = c0m; kp.c1m = c1m; kp.outp = outp;
  kp.out = (float*)d_out;
  kp.bar = bar; kp.rel = rel; kp.assign = assign;

  void* kargs[] = { &kp };
  hipError_t ce = hipLaunchCooperativeKernel((void*)lstm_persist,
                                             dim3(NBLOCKS), dim3(256), kargs, 0, stream);
  if (ce != hipSuccess){
    for (int s = 0; s <= TT; ++s)
      fb_enc<<<NBLOCKS, 256, 0, stream>>>(kp, s);
    int p0 = 1, p1 = 1;
    for (int d = 0; d < NSTEPS; ++d){
      fb_dec0<<<256, 256, 0, stream>>>(kp, d, p0);
      fb_dec1<<<256, 256, 0, stream>>>(kp, p0, p1);
      fb_lin<<<32, 256, 0, stream>>>(kp, d, p1);
      p0 ^= 1; p1 ^= 1;
    }
  }
}